// Round 18
// baseline (93.600 us; speedup 1.0000x reference)
//
#include <hip/hip_runtime.h>
#include <hip/hip_bf16.h>

#define B_TOTAL 65536
#define NR 4
#define VD 100
#define HD 200
#define DK 32
#define MH 128
#define RD 64

typedef __attribute__((ext_vector_type(8))) short bf16x8;
typedef __attribute__((ext_vector_type(4))) float f32x4;
typedef __attribute__((ext_vector_type(4))) double f64x4;

static __device__ inline unsigned short f2bf(float x) {
    __hip_bfloat16 h = __float2bfloat16(x);
    return __builtin_bit_cast(unsigned short, h);
}

// ---- workspace layout (bytes) ---- total 975,360 (< 1.41 MB proven in R1)
#define WS_GF    0         // 76*64*8 = 38912 (G in f64 MFMA B-fragment layout)
#define WS_PM    38912     // 64*4*4 = 1024 (probed C-layout row map)
#define WS_PN    39936     // 64*4*4 = 1024 (probed C-layout col map)
#define WS_CNT   40960     // 16
#define WS_LIST  41472     // 4*65536*2 = 524288
#define WS_VB    565760    // 65536
#define WS_W1F   631296    // 229376
#define WS_W2F   860672    // 114688

// ---------------- kernel 0a: G fragment + C/D-layout PROBE + zero counters ----------------
// scores(row, p=r*2+v) = sum_k X[row][k] * G304[k][p], K=304 (zero-padded):
//   k<100   : h[0][k]    contributes to p even (v=0) via Wk row k
//   100..200: h[1][k-100] -> p odd (v=1) via Wk row 200+(k-100)
//   200..300: h[2][k-200] -> all p via Wk row v*200+100+(k-200)
//   300..304: 0
// B-fragment (family-consistent, HW-verified for 5 dtypes): lane l holds
// B[k = ks*4 + (l>>4)][col = l&15]. Cols 8..15 zero.
// PROBE: the f64 16x16x4 C/D lane->((row,col)) map is the ONE cell not
// covered by m89's dtype-independence verification (R15 failed with absmax
// 1.84 = row-permutation signature). Two identity MFMAs discover it:
//   D1[m][n] = m  (A[m][k]=m*d(k==0), B=1)   -> pm[lane][reg] = row
//   D2[m][n] = n  (A=d(k==0),   B[k][n]=n)   -> pn[lane][reg] = col
// Both probes are k-map-agnostic (uniform in k) and valid for ANY bijective
// C layout.
__global__ __launch_bounds__(256) void k0_prep(
    const float* __restrict__ rule_emb, const float* __restrict__ Wq,
    const float* __restrict__ bq, const float* __restrict__ Wk,
    double* __restrict__ Gf, int* __restrict__ pm, int* __restrict__ pn,
    int* __restrict__ cnt)
{
    int tid = threadIdx.x;
    if (tid < NR) cnt[tid] = 0;

    // C/D layout probe (wave 0 only, full wave)
    if (tid < 64) {
        int l = tid;
        f64x4 z = {0.0, 0.0, 0.0, 0.0};
        double a1 = ((l >> 4) == 0) ? (double)(l & 15) : 0.0;
        f64x4 d1 = __builtin_amdgcn_mfma_f64_16x16x4f64(a1, 1.0, z, 0, 0, 0);
        double a2 = ((l >> 4) == 0) ? 1.0 : 0.0;
        double b2 = (double)(l & 15);
        f64x4 d2 = __builtin_amdgcn_mfma_f64_16x16x4f64(a2, b2, z, 0, 0, 0);
#pragma unroll
        for (int j = 0; j < 4; ++j) {
            pm[l * 4 + j] = (int)(d1[j] + 0.5);
            pn[l * 4 + j] = (int)(d2[j] + 0.5);
        }
    }

    __shared__ double readS[NR * DK];
    if (tid < NR * DK) {
        int r = tid >> 5, k = tid & 31;
        double a = (double)bq[k];
        for (int d = 0; d < RD; ++d)
            a += (double)rule_emb[r * RD + d] * (double)Wq[d * DK + k];
        readS[tid] = a;
    }
    __syncthreads();

    for (int i = tid; i < 76 * 64; i += 256) {
        int ks = i >> 6, l = i & 63;
        int k = ks * 4 + (l >> 4), c = l & 15;
        double g = 0.0;
        if (c < 8 && k < 300) {
            int r = c >> 1, v = c & 1;
            int wrow = -1;
            if (k < 100)        { if (v == 0) wrow = k; }
            else if (k < 200)   { if (v == 1) wrow = 200 + (k - 100); }
            else                { wrow = v * 200 + 100 + (k - 200); }
            if (wrow >= 0)
                for (int kk = 0; kk < DK; ++kk)
                    g += (double)Wk[wrow * DK + kk] * readS[r * DK + kk];
        }
        Gf[i] = g;
    }
}

// ---------------- kernel 0b: W1/W2 -> bf16 MFMA B-fragment layout ----------------
__global__ __launch_bounds__(256) void k0_wfrag(
    const float* __restrict__ W1, const float* __restrict__ W2,
    unsigned short* __restrict__ W1f, unsigned short* __restrict__ W2f)
{
    int i = blockIdx.x * 256 + threadIdx.x;
    if (i < 114688) {
        int r = i / 28672, rem = i % 28672;
        int ks = rem / 4096, rem2 = rem % 4096;
        int n = rem2 >> 9, l = (rem2 >> 3) & 63, j = rem2 & 7;
        int k = ks * 32 + ((l >> 4) << 3) + j;
        int c = n * 16 + (l & 15);
        float v = (k < HD) ? W1[((size_t)r * HD + k) * MH + c] : 0.f;
        W1f[i] = f2bf(v);
    } else if (i < 114688 + 57344) {
        int t = i - 114688;
        int r = t / 14336, rem = t % 14336;
        int ks = rem / 3584, rem2 = rem % 3584;
        int n = rem2 >> 9, l = (rem2 >> 3) & 63, j = rem2 & 7;
        int k = ks * 32 + ((l >> 4) << 3) + j;
        int c = n * 16 + (l & 15);
        float v = (c < VD) ? W2[((size_t)r * MH + k) * VD + c] : 0.f;
        W2f[t] = f2bf(v);
    }
}

// ---------------- kernel 1: selection via fp64 MFMA (probed C layout) ----------------
// v12 = R15's v11 structure (coalesced 64-row LDS stage, 76 x
// v_mfma_f64_16x16x4, Gf fragment table) with the C/D attribution done via
// the RUNTIME-PROBED maps: lane l's acc[j] is score(row pm[l][j], col
// pn[l][j]) -- scatter to LDS scf[row][col], then per-row serial argmax
// (ascending p, first-occurrence = jnp.argmax) + proven bucket logic.
__global__ __launch_bounds__(256) void k1_select(
    const float* __restrict__ hidden, const double* __restrict__ Gf,
    const int* __restrict__ pm, const int* __restrict__ pn,
    int* __restrict__ cnt, unsigned short* __restrict__ list16,
    unsigned char* __restrict__ vbyte)
{
    __shared__ float hs[64 * 308];     // 78848 B
    __shared__ double scf[64][9];      // 4608 B (pad 9)
    __shared__ int lcnt[NR];
    __shared__ int lbase[NR];
    int tid = threadIdx.x;
    if (tid < NR) lcnt[tid] = 0;

    int rowbase = blockIdx.x * 64;

    // stage 64 rows, fully coalesced (4800 float4, linear)
    const float4* src4 = (const float4*)(hidden + (size_t)rowbase * 300);
#pragma unroll
    for (int k = 0; k < 19; ++k) {
        int idx = tid + k * 256;
        if (idx < 4800) {
            int row = idx / 75, c4 = idx - row * 75;
            *(float4*)&hs[row * 308 + c4 * 4] = src4[idx];
        }
    }
    // zero-pad k = [300,308)
    if (tid < 128) {
        int row = tid >> 1, part = tid & 1;
        *(float4*)&hs[row * 308 + 300 + part * 4] = make_float4(0.f, 0.f, 0.f, 0.f);
    }
    __syncthreads();

    int lane = tid & 63, wave = tid >> 6;
    int arow = wave * 16 + (lane & 15);   // A: row = l&15 (family-verified)
    int klane = lane >> 4;                // A/B: k-group = l>>4

    f64x4 acc = {0.0, 0.0, 0.0, 0.0};
#pragma unroll 4
    for (int ks = 0; ks < 76; ++ks) {
        double a = (double)hs[arow * 308 + ks * 4 + klane];
        double b = Gf[ks * 64 + lane];
        acc = __builtin_amdgcn_mfma_f64_16x16x4f64(a, b, acc, 0, 0, 0);
    }

    // scatter accs to (row, col) via probed maps; cols 8..15 are zero-G, skip
#pragma unroll
    for (int j = 0; j < 4; ++j) {
        int m = pm[lane * 4 + j];
        int n = pn[lane * 4 + j];
        if (n < 8) scf[wave * 16 + m][n] = acc[j];
    }
    __syncthreads();

    // per-row argmax (ascending p, first occurrence) + bucket compaction
    int r = 0, v = 0, pos = 0;
    if (tid < 64) {
        double bv = scf[tid][0]; int best = 0;
#pragma unroll
        for (int p = 1; p < 8; ++p) {
            double s = scf[tid][p];
            if (s > bv) { bv = s; best = p; }
        }
        r = best >> 1; v = best & 1;
        vbyte[rowbase + tid] = (unsigned char)v;
        pos = atomicAdd(&lcnt[r], 1);
    }
    __syncthreads();
    if (tid < NR) lbase[tid] = atomicAdd(&cnt[tid], lcnt[tid]);
    __syncthreads();
    if (tid < 64) list16[r * B_TOTAL + lbase[r] + pos] = (unsigned short)(rowbase + tid);
}

// ---------------- kernel 2: bucketed bf16-MFMA MLP ----------------
// v3 (proven R9-R14: ~15us): 64-row tiles, LDS 30KB, ~5 blocks/CU;
// 4 threads/row staging with 13 batched float4.
__global__ __launch_bounds__(256) void k2_mlp(
    const float* __restrict__ hidden,
    const unsigned short* __restrict__ W1f, const unsigned short* __restrict__ W2f,
    const int* __restrict__ cnt, const unsigned short* __restrict__ list16,
    const unsigned char* __restrict__ vbyte, float* __restrict__ out)
{
    int r = blockIdx.y;
    int nb = cnt[r];
    int m0 = blockIdx.x * 64;
    if (m0 >= nb) return;
    int me = nb - m0; if (me > 64) me = 64;

    __shared__ __align__(16) unsigned short shbuf[64 * 232]; // X [64][232]; C1 overlay [64][136]
    __shared__ int ent[64];

    int tid = threadIdx.x;
    int wave = tid >> 6, lane = tid & 63;
    int lr = lane & 15, lk = lane >> 4;
    int wrow0 = wave * 16;

    if (tid < 64) {
        int idx = m0 + tid; if (idx > nb - 1) idx = nb - 1;
        int b = list16[r * B_TOTAL + idx];
        int v = vbyte[b];
        ent[tid] = (b << 1) | v;
    }
    __syncthreads();

    // stage X: thread = (e, h, t): e=tid>>2 row, h=(tid>>1)&1 seg-half,
    // t=tid&1 sub-half. 13 consecutive float4 batched into regs.
    {
        int e = tid >> 2, hh = (tid >> 1) & 1, t = tid & 1;
        int en = ent[e];
        int b = en >> 1, v = en & 1;
        int seg = hh ? (1 - v) : v;
        int q0 = t * 12;   // 0..12 / 12..24 (chunk 12 written twice, same value)
        const float4* src = (const float4*)(hidden + (size_t)b * 300 + seg * 100) + q0;
        float4 hv[13];
#pragma unroll
        for (int u = 0; u < 13; ++u) hv[u] = src[u];
#pragma unroll
        for (int u = 0; u < 13; ++u) {
            ushort4 o;
            o.x = f2bf(hv[u].x); o.y = f2bf(hv[u].y);
            o.z = f2bf(hv[u].z); o.w = f2bf(hv[u].w);
            *(ushort4*)&shbuf[e * 232 + (hh * 25 + q0 + u) * 4] = o;
        }
    }
    // zero-pad k = [200,232) fully: 4 bf16x8 chunks per row (NaN-laundering
    // hazard: stale LDS * 0-weight = NaN -> relu -> zeroed rows).
    {
        int row = tid >> 2, part = tid & 3;
        bf16x8 z = {0, 0, 0, 0, 0, 0, 0, 0};
        *(bf16x8*)&shbuf[row * 232 + 200 + part * 8] = z;
    }
    __syncthreads();

    // ---- GEMM1 ----
    const unsigned short* W1f_r = W1f + (size_t)r * 28672;
    f32x4 acc1[8];
#pragma unroll
    for (int n = 0; n < 8; ++n) acc1[n] = (f32x4){0.f, 0.f, 0.f, 0.f};

#pragma unroll
    for (int ks = 0; ks < 7; ++ks) {
        bf16x8 a0 = *(const bf16x8*)&shbuf[(wrow0 + lr) * 232 + ks * 32 + lk * 8];
#pragma unroll
        for (int n = 0; n < 8; ++n) {
            bf16x8 bfr = *(const bf16x8*)&W1f_r[(size_t)(ks * 8 + n) * 512 + lane * 8];
            acc1[n] = __builtin_amdgcn_mfma_f32_16x16x32_bf16(a0, bfr, acc1[n], 0, 0, 0);
        }
    }

    __syncthreads();  // all waves done reading X before overlay

    // relu -> bf16 -> C1 transpose-store: row=wrow0+(lane>>4)*4+j, col=n*16+(lane&15)
#pragma unroll
    for (int n = 0; n < 8; ++n)
#pragma unroll
        for (int j = 0; j < 4; ++j) {
            float v = fmaxf(acc1[n][j], 0.f);
            int row = wrow0 + lk * 4 + j;
            shbuf[row * 136 + n * 16 + lr] = f2bf(v);
        }
    __syncthreads();

    // ---- GEMM2 ----
    const unsigned short* W2f_r = W2f + (size_t)r * 14336;
    f32x4 acc2[7];
#pragma unroll
    for (int n = 0; n < 7; ++n) acc2[n] = (f32x4){0.f, 0.f, 0.f, 0.f};

#pragma unroll
    for (int ks = 0; ks < 4; ++ks) {
        bf16x8 a0 = *(const bf16x8*)&shbuf[(wrow0 + lr) * 136 + ks * 32 + lk * 8];
#pragma unroll
        for (int n = 0; n < 7; ++n) {
            bf16x8 bfr = *(const bf16x8*)&W2f_r[(size_t)(ks * 7 + n) * 512 + lane * 8];
            acc2[n] = __builtin_amdgcn_mfma_f32_16x16x32_bf16(a0, bfr, acc2[n], 0, 0, 0);
        }
    }

    // scatter-store
#pragma unroll
    for (int n = 0; n < 7; ++n) {
        int col = n * 16 + lr;
        if (col < VD) {
#pragma unroll
            for (int j = 0; j < 4; ++j) {
                int e = wrow0 + lk * 4 + j;
                if (e < me) {
                    int b = ent[e] >> 1;
                    out[(size_t)b * VD + col] = acc2[n][j];
                }
            }
        }
    }
}

extern "C" void kernel_launch(void* const* d_in, const int* in_sizes, int n_in,
                              void* d_out, int out_size, void* d_ws, size_t ws_size,
                              hipStream_t stream) {
    (void)in_sizes; (void)n_in; (void)out_size; (void)ws_size;
    const float* hidden   = (const float*)d_in[0];
    const float* rule_emb = (const float*)d_in[1];
    const float* Wq       = (const float*)d_in[2];
    const float* bq       = (const float*)d_in[3];
    const float* Wk       = (const float*)d_in[4];
    const float* W1       = (const float*)d_in[5];
    const float* W2       = (const float*)d_in[6];
    float* out = (float*)d_out;

    char* ws = (char*)d_ws;
    double* Gf             = (double*)(ws + WS_GF);
    int* pm                = (int*)(ws + WS_PM);
    int* pn                = (int*)(ws + WS_PN);
    int* cnt               = (int*)(ws + WS_CNT);
    unsigned short* list16 = (unsigned short*)(ws + WS_LIST);
    unsigned char* vbyte   = (unsigned char*)(ws + WS_VB);
    unsigned short* W1f    = (unsigned short*)(ws + WS_W1F);
    unsigned short* W2f    = (unsigned short*)(ws + WS_W2F);

    k0_prep<<<1, 256, 0, stream>>>(rule_emb, Wq, bq, Wk, Gf, pm, pn, cnt);
    k0_wfrag<<<672, 256, 0, stream>>>(W1, W2, W1f, W2f);
    k1_select<<<1024, 256, 0, stream>>>(hidden, Gf, pm, pn, cnt, list16, vbyte);
    k2_mlp<<<dim3(1024, NR), 256, 0, stream>>>(hidden, W1f, W2f, cnt, list16, vbyte, out);
}